// Round 5
// baseline (646.229 us; speedup 1.0000x reference)
//
#include <hip/hip_runtime.h>
#include <cfloat>

// Problem constants (MoMEAdaptor): B=2,S=1024,H=2048,D=256,R=32,K=4,NDB=100000
#define B_   2
#define S_   1024
#define H_   2048
#define D_   256
#define R_   32
#define K_   4
#define NDB_ 100000
#define KN_PAD 2048

// Only queries (b, t<256) feed the attention (mask j<=i => j<1024 => t<256).
#define TSEL 256
#define NSEL (B_ * TSEL)          // 512 queries that need k-NN

// MFMA knn tiling (swapped-operand path)
#define NCHUNK     131            // db chunks
#define CHUNK_ROWS 768            // 6 tiles * 128
#define TILES      6
#define MTQ        128            // queries per block

// fp32 fallback tiling
#define FB_NCHUNK     61
#define FB_CHUNK_ROWS 1664
#define FB_TILES      13
#define MT         64
#define KC         64
#define LSTR       68

#define NEG_INF  (-3.0e38f)
#define IDX_MAX  0x7fffffff

// Workspace layout (bytes). need = 0x900000 + 51.2MB ~= 60.6 MB
// ps overlays KVT, pi overlays KVV (consumed before k_gather writes them).
#define OFF_Q     0          // 2048*256 f32            (2 MB)
#define OFF_KN    0x200000   // (100000+2048) f32       (<512 KB)
#define OFF_IDX   0x280000   // 2048 i32
#define OFF_CAND  0x290000   // 512*16 i32
#define OFF_KVT   0x300000   // keys transposed [2][256][1024] f32 (2 MB) | ps overlay
#define OFF_AO    0x500000   // attention out [2048][256] f32 (2 MB)
#define OFF_KVV   0x700000   // values dense [2][1024][256] f32 (2 MB)   | pi overlay
#define OFF_DBK16 0x900000   // bf16 db copy 100000*256*2 = 51.2 MB

typedef unsigned short ushort_t;
typedef unsigned int   uint_t;
typedef __attribute__((ext_vector_type(8)))  __bf16 bf16x8;
typedef __attribute__((ext_vector_type(16))) float  f32x16;

// sorted-insert of (score,idx) into descending top-4; ties -> lower index first
__device__ __forceinline__ void ins4(float sc, int n, float s[4], int id[4]) {
  if (sc > s[3] || (sc == s[3] && n < id[3])) {
    s[3] = sc; id[3] = n;
#pragma unroll
    for (int k = 3; k > 0; --k) {
      if (s[k] > s[k - 1] || (s[k] == s[k - 1] && id[k] < id[k - 1])) {
        float ts = s[k]; s[k] = s[k - 1]; s[k - 1] = ts;
        int ti = id[k]; id[k] = id[k - 1]; id[k - 1] = ti;
      }
    }
  }
}

__device__ __forceinline__ uint_t bfpack(float a, float b) {   // 2x fp32 -> packed bf16 (RNE)
  uint_t ua = __float_as_uint(a), ub = __float_as_uint(b);
  ua = (ua + 0x7fffu + ((ua >> 16) & 1u)) >> 16;
  ub = (ub + 0x7fffu + ((ub >> 16) & 1u)) >> 16;
  return ua | (ub << 16);
}

// ---------------- q = (hidden @ wq_in) @ wq_out,  one block per token ----------------
__global__ __launch_bounds__(256) void k_compute_q(
    const float* __restrict__ hidden, const float* __restrict__ wq_in,
    const float* __restrict__ wq_out, float* __restrict__ q) {
  __shared__ float hrow[H_];
  __shared__ float part[8][R_];
  __shared__ float q1[R_];
  const int m = blockIdx.x;
  const int t = threadIdx.x;
  const float* hp = hidden + (size_t)m * H_;
  ((float4*)hrow)[t]       = ((const float4*)hp)[t];
  ((float4*)hrow)[t + 256] = ((const float4*)hp)[t + 256];
  __syncthreads();
  const int r = t & 31, c = t >> 5;
  float p = 0.f;
#pragma unroll 4
  for (int e = c * 256; e < c * 256 + 256; ++e)
    p = fmaf(hrow[e], wq_in[(size_t)e * R_ + r], p);
  part[c][r] = p;
  __syncthreads();
  if (t < R_) {
    float s = 0.f;
#pragma unroll
    for (int cc = 0; cc < 8; ++cc) s += part[cc][t];
    q1[t] = s;
  }
  __syncthreads();
  float acc = 0.f;
#pragma unroll
  for (int rr = 0; rr < R_; ++rr) acc = fmaf(q1[rr], wq_out[rr * D_ + t], acc);
  q[(size_t)m * D_ + t] = acc;
}

// ------- kn[n] = |db_keys[n]|^2 (+ fused bf16 conversion, + 1e30 tail pad) -------
__global__ __launch_bounds__(256) void k_kn_cvt(const float* __restrict__ dbk,
                                               float* __restrict__ kn,
                                               ushort_t* __restrict__ dbk16) {
  const int w = threadIdx.x >> 6, l = threadIdx.x & 63;
  const int n = blockIdx.x * 4 + w;
  if (n >= NDB_ + KN_PAD) return;
  if (n >= NDB_) { if (l == 0) kn[n] = 1.0e30f; return; }
  const float4 v = ((const float4*)(dbk + (size_t)n * D_))[l];
  uint2 p; p.x = bfpack(v.x, v.y); p.y = bfpack(v.z, v.w);
  ((uint2*)(dbk16 + (size_t)n * D_))[l] = p;
  float s = v.x * v.x + v.y * v.y + v.z * v.z + v.w * v.w;
#pragma unroll
  for (int off = 32; off; off >>= 1) s += __shfl_down(s, off);
  if (l == 0) kn[n] = s;
}

// plain kn (fallback path)
__global__ __launch_bounds__(256) void k_kn(const float* __restrict__ dbk,
                                            float* __restrict__ kn) {
  const int w = threadIdx.x >> 6, l = threadIdx.x & 63;
  const int n = blockIdx.x * 4 + w;
  if (n >= NDB_) return;
  const float4 v = ((const float4*)(dbk + (size_t)n * D_))[l];
  float s = v.x * v.x + v.y * v.y + v.z * v.z + v.w * v.w;
#pragma unroll
  for (int off = 32; off; off >>= 1) s += __shfl_down(s, off);
  if (l == 0) kn[n] = s;
}

// ------------- swapped-operand bf16 MFMA knn: per-(qb, chunk) partial top-4 -------------
// D[db_row][query]: A = db rows (direct global->VGPR dwordx4, NO LDS, NO barriers in the
// main loop), B = q fragments from LDS (128 q rows bf16, XOR-swizzled, 64 KB).
// C layout: col=lane&31 = query  =>  per-lane in-register top-4 (one query per acc).
// score = 2*(q.k)_bf16 - kn_fp32; kn tail (>=NDB) = 1e30 self-excludes padded rows.
// Exact fp32 rescore of global top-16 picks the final indices.
__global__ __launch_bounds__(256, 2) void k_knn_mfma(
    const float* __restrict__ q, const ushort_t* __restrict__ dbk16,
    const float* __restrict__ kn, float* __restrict__ pscore,
    int* __restrict__ pidx) {
  __shared__ __align__(16) ushort_t sA16[MTQ * 256];   // 64 KB

  const int tid = threadIdx.x;
  const int w = tid >> 6, ln = tid & 63;
  const int lm = ln & 31, lh = ln >> 5;
  const int qb = blockIdx.x, chunk = blockIdx.y;
  const int row_base = chunk * CHUNK_ROWS;

  // ---- stage 128 selected q rows -> bf16, 16B-chunk XOR swizzle ----
  {
    const int m = tid >> 1, h = tid & 1;
    const int sq = qb * MTQ + m;
    const float* qp = q + ((size_t)((sq >> 8) * S_ + (sq & 255))) * D_;
#pragma unroll
    for (int ci = 0; ci < 16; ++ci) {
      const int c = h * 16 + ci;
      const float4 v0 = *(const float4*)(qp + c * 8);
      const float4 v1 = *(const float4*)(qp + c * 8 + 4);
      uint4 pk;
      pk.x = bfpack(v0.x, v0.y); pk.y = bfpack(v0.z, v0.w);
      pk.z = bfpack(v1.x, v1.y); pk.w = bfpack(v1.z, v1.w);
      *(uint4*)&sA16[(m * 32 + (c ^ (m & 7))) * 8] = pk;
    }
  }
  __syncthreads();

  float s4[4][4]; int i4[4][4];
#pragma unroll
  for (int g = 0; g < 4; ++g)
#pragma unroll
    for (int k = 0; k < 4; ++k) { s4[g][k] = NEG_INF; i4[g][k] = IDX_MAX; }

  const int aswz = lm & 7;

  for (int tile = 0; tile < TILES; ++tile) {
    const int row0 = row_base + tile * 128;
    int rowA = row0 + w * 32 + lm; if (rowA >= NDB_) rowA = NDB_ - 1;
    const ushort_t* ap = dbk16 + (size_t)rowA * D_ + lh * 8;

    // A frags for the whole tile: 16 x dwordx4 in flight
    bf16x8 aF[16];
#pragma unroll
    for (int ks = 0; ks < 16; ++ks)
      aF[ks] = *(const bf16x8*)(ap + ks * 16);

    // kn for this lane's 16 rows (uniform per 32-lane half -> broadcast loads)
    const int knb = row0 + w * 32 + lh * 4;
    const float4 kf0 = *(const float4*)&kn[knb];
    const float4 kf1 = *(const float4*)&kn[knb + 8];
    const float4 kf2 = *(const float4*)&kn[knb + 16];
    const float4 kf3 = *(const float4*)&kn[knb + 24];
    const float karr[16] = {kf0.x, kf0.y, kf0.z, kf0.w, kf1.x, kf1.y, kf1.z, kf1.w,
                            kf2.x, kf2.y, kf2.z, kf2.w, kf3.x, kf3.y, kf3.z, kf3.w};

    f32x16 acc[4];
#pragma unroll
    for (int g = 0; g < 4; ++g)
#pragma unroll
      for (int r = 0; r < 16; ++r) acc[g][r] = 0.f;

#pragma unroll
    for (int ks = 0; ks < 16; ++ks) {
      const int pos = ((ks * 2 + lh) ^ aswz) * 8;
#pragma unroll
      for (int g = 0; g < 4; ++g) {
        const bf16x8 bq = *(const bf16x8*)&sA16[(g * 32 + lm) * 256 + pos];
        acc[g] = __builtin_amdgcn_mfma_f32_32x32x16_bf16(aF[ks], bq, acc[g], 0, 0, 0);
      }
    }

    // ---- in-register select: lane owns query g*32+lm; 16 rows per acc ----
#pragma unroll
    for (int g = 0; g < 4; ++g) {
      float v[16];
#pragma unroll
      for (int r = 0; r < 16; ++r) v[r] = fmaf(2.f, acc[g][r], -karr[r]);
      float mx = v[0];
#pragma unroll
      for (int r = 1; r < 16; ++r) mx = fmaxf(mx, v[r]);
      if (mx >= s4[g][3]) {
#pragma unroll
        for (int r = 0; r < 16; ++r) {
          const int n = row0 + w * 32 + (r >> 2) * 8 + 4 * lh + (r & 3);
          ins4(v[r], n, s4[g], i4[g]);
        }
      }
    }
  }

  // ---- block merge: 32 candidates per query (4 waves x 2 lh x 4) -> top-4 ----
  __syncthreads();   // done reading sA16
  float* cs = (float*)sA16;                                 // [128][33]
  int*   ci = (int*)((char*)sA16 + 128 * 33 * 4 + 64);      // [128][33]
#pragma unroll
  for (int g = 0; g < 4; ++g) {
    const int qrow = g * 32 + lm;
    const int src = w * 8 + lh * 4;
#pragma unroll
    for (int k = 0; k < 4; ++k) {
      cs[qrow * 33 + src + k] = s4[g][k];
      ci[qrow * 33 + src + k] = i4[g][k];
    }
  }
  __syncthreads();
  if (tid < MTQ) {
    float fs[4]; int fi[4];
#pragma unroll
    for (int k = 0; k < 4; ++k) { fs[k] = NEG_INF; fi[k] = IDX_MAX; }
    for (int c = 0; c < 32; ++c)
      ins4(cs[tid * 33 + c], ci[tid * 33 + c], fs, fi);
    const int sq = qb * MTQ + tid;
    float* po = pscore + ((size_t)sq * NCHUNK + chunk) * 4;
    int*   io = pidx   + ((size_t)sq * NCHUNK + chunk) * 4;
#pragma unroll
    for (int k = 0; k < 4; ++k) { po[k] = fs[k]; io[k] = fi[k]; }
  }
}

// ---------------- fp32 fallback knn (round-1 kernel, used if ws too small) ----------------
__global__ __launch_bounds__(256) void k_knn_partial(
    const float* __restrict__ q, const float* __restrict__ dbk,
    const float* __restrict__ kn, float* __restrict__ pscore,
    int* __restrict__ pidx) {
  __shared__ float smem[3 * KC * LSTR];
  float* sA  = smem;
  float* sB0 = smem + KC * LSTR;
  float* sB1 = smem + 2 * KC * LSTR;
  const int tid = threadIdx.x;
  const int tx = tid & 15, ty = tid >> 4;
  const int chunk = blockIdx.x, qb = blockIdx.y;
  const int arq = tid >> 2;
  const int aqd = (tid & 3) * 4;
  const int brk = tid >> 1;
  const int bh  = tid & 1;
  const int bcol = ((brk >> 3) << 2) | (brk & 3);
  float* sBw = (brk & 4) ? sB1 : sB0;
  const int sq_a = qb * MT + arq;
  const float* qsrc = q + ((size_t)((sq_a >> 8) * S_ + (sq_a & 255))) * D_;
  float s4[4][4]; int i4[4][4];
#pragma unroll
  for (int a = 0; a < 4; ++a)
#pragma unroll
    for (int b = 0; b < 4; ++b) { s4[a][b] = NEG_INF; i4[a][b] = IDX_MAX; }
  const int row_base = chunk * FB_CHUNK_ROWS;
  for (int tile = 0; tile < FB_TILES; ++tile) {
    const int row0 = row_base + tile * 128;
    if (row0 >= NDB_) break;
    int krow = row0 + brk; if (krow >= NDB_) krow = NDB_ - 1;
    const float* ksrc = dbk + (size_t)krow * D_;
    float acc[4][8];
#pragma unroll
    for (int a = 0; a < 4; ++a)
#pragma unroll
      for (int b = 0; b < 8; ++b) acc[a][b] = 0.f;
    for (int kc = 0; kc < 4; ++kc) {
      __syncthreads();
#pragma unroll
      for (int p = 0; p < 4; ++p) {
        const int kkl = p * 16 + aqd;
        const float4 v = *(const float4*)(qsrc + kc * KC + kkl);
        sA[(kkl + 0) * LSTR + arq] = v.x;
        sA[(kkl + 1) * LSTR + arq] = v.y;
        sA[(kkl + 2) * LSTR + arq] = v.z;
        sA[(kkl + 3) * LSTR + arq] = v.w;
      }
#pragma unroll
      for (int p = 0; p < 8; ++p) {
        const int kkl = bh * 32 + p * 4;
        const float4 v = *(const float4*)(ksrc + kc * KC + kkl);
        sBw[(kkl + 0) * LSTR + bcol] = v.x;
        sBw[(kkl + 1) * LSTR + bcol] = v.y;
        sBw[(kkl + 2) * LSTR + bcol] = v.z;
        sBw[(kkl + 3) * LSTR + bcol] = v.w;
      }
      __syncthreads();
#pragma unroll 4
      for (int kk = 0; kk < KC; ++kk) {
        const float4 a  = *(const float4*)&sA [kk * LSTR + ty * 4];
        const float4 b0 = *(const float4*)&sB0[kk * LSTR + tx * 4];
        const float4 b1 = *(const float4*)&sB1[kk * LSTR + tx * 4];
        const float av[4] = {a.x, a.y, a.z, a.w};
        const float bv[8] = {b0.x, b0.y, b0.z, b0.w, b1.x, b1.y, b1.z, b1.w};
#pragma unroll
        for (int qi = 0; qi < 4; ++qi)
#pragma unroll
          for (int nj = 0; nj < 8; ++nj)
            acc[qi][nj] = fmaf(av[qi], bv[nj], acc[qi][nj]);
      }
    }
#pragma unroll
    for (int nj = 0; nj < 8; ++nj) {
      const int n = row0 + tx * 8 + nj;
      if (n < NDB_) {
        const float knj = kn[n];
        ins4(2.f * acc[0][nj] - knj, n, s4[0], i4[0]);
        ins4(2.f * acc[1][nj] - knj, n, s4[1], i4[1]);
        ins4(2.f * acc[2][nj] - knj, n, s4[2], i4[2]);
        ins4(2.f * acc[3][nj] - knj, n, s4[3], i4[3]);
      }
    }
  }
  __syncthreads();
  float* cs = smem;
  int*   ci = (int*)(smem + 64 * 65);
#pragma unroll
  for (int qi = 0; qi < 4; ++qi)
#pragma unroll
    for (int k = 0; k < 4; ++k) {
      cs[(ty * 4 + qi) * 65 + tx * 4 + k] = s4[qi][k];
      ci[(ty * 4 + qi) * 65 + tx * 4 + k] = i4[qi][k];
    }
  __syncthreads();
  if (tid < 64) {
    float fs[4]; int fi[4];
#pragma unroll
    for (int k = 0; k < 4; ++k) { fs[k] = NEG_INF; fi[k] = IDX_MAX; }
    for (int c = 0; c < 64; ++c)
      ins4(cs[tid * 65 + c], ci[tid * 65 + c], fs, fi);
    const int sq = qb * MT + tid;
    float* po = pscore + ((size_t)sq * FB_NCHUNK + chunk) * 4;
    int*   io = pidx   + ((size_t)sq * FB_NCHUNK + chunk) * 4;
#pragma unroll
    for (int k = 0; k < 4; ++k) { po[k] = fs[k]; io[k] = fi[k]; }
  }
}

// ---------------- merge chunk candidates -> sorted global top-R ----------------
template <int RANKS>
__device__ __forceinline__ void merge_top(const float* __restrict__ pscore,
                                          const int* __restrict__ pidx,
                                          int* __restrict__ outp, int nch) {
  const int sq = blockIdx.x, l = threadIdx.x;
  float s4[4]; int i4[4];
#pragma unroll
  for (int k = 0; k < 4; ++k) { s4[k] = NEG_INF; i4[k] = IDX_MAX; }
  for (int c = l; c < nch * 4; c += 64)
    ins4(pscore[(size_t)sq * nch * 4 + c], pidx[(size_t)sq * nch * 4 + c], s4, i4);
#pragma unroll
  for (int r = 0; r < RANKS; ++r) {
    float s = s4[0]; int i = i4[0];
#pragma unroll
    for (int off = 32; off; off >>= 1) {
      float so = __shfl_down(s, off); int io = __shfl_down(i, off);
      if (so > s || (so == s && io < i)) { s = so; i = io; }
    }
    const float sw = __shfl(s, 0); const int iw = __shfl(i, 0);
    if (l == 0) outp[sq * RANKS + r] = iw;
    if (s4[0] == sw && i4[0] == iw) {
      s4[0] = s4[1]; i4[0] = i4[1];
      s4[1] = s4[2]; i4[1] = i4[2];
      s4[2] = s4[3]; i4[2] = i4[3];
      s4[3] = NEG_INF; i4[3] = IDX_MAX;
    }
  }
}

__global__ __launch_bounds__(64) void k_knn_merge4(const float* __restrict__ ps,
                                                   const int* __restrict__ pi,
                                                   int* __restrict__ knn_idx, int nch) {
  merge_top<4>(ps, pi, knn_idx, nch);
}
__global__ __launch_bounds__(64) void k_knn_merge16(const float* __restrict__ ps,
                                                    const int* __restrict__ pi,
                                                    int* __restrict__ cand, int nch) {
  merge_top<16>(ps, pi, cand, nch);
}

// ---------------- exact fp32 rescore of 16 candidates -> final sorted top-4 ----------------
__global__ __launch_bounds__(256) void k_rescore(const float* __restrict__ q,
                                                 const float* __restrict__ dbk,
                                                 const float* __restrict__ kn,
                                                 const int* __restrict__ cand,
                                                 int* __restrict__ knn_idx) {
  __shared__ float scs[16];
  __shared__ int   sci[16];
  const int sq = blockIdx.x, wv = threadIdx.x >> 6, l = threadIdx.x & 63;
  const float* qp = q + ((size_t)((sq >> 8) * S_ + (sq & 255))) * D_;
  const float4 qv = ((const float4*)qp)[l];
  for (int cc = wv; cc < 16; cc += 4) {
    const int n = cand[sq * 16 + cc];
    const float4 kv = ((const float4*)(dbk + (size_t)n * D_))[l];
    float s = qv.x * kv.x + qv.y * kv.y + qv.z * kv.z + qv.w * kv.w;
#pragma unroll
    for (int off = 32; off; off >>= 1) s += __shfl_down(s, off);
    if (l == 0) { scs[cc] = 2.f * s - kn[n]; sci[cc] = n; }
  }
  __syncthreads();
  if (threadIdx.x == 0) {
    float s4[4]; int i4[4];
#pragma unroll
    for (int k = 0; k < 4; ++k) { s4[k] = NEG_INF; i4[k] = IDX_MAX; }
#pragma unroll
    for (int c = 0; c < 16; ++c) ins4(scs[c], sci[c], s4, i4);
#pragma unroll
    for (int k = 0; k < 4; ++k) knn_idx[sq * 4 + k] = i4[k];
  }
}

// -------- gather: keys transposed kvT[b][d][j] + values dense kvV[b][j][d] --------
__global__ __launch_bounds__(256) void k_gather(const float* __restrict__ dbk,
                                                const float* __restrict__ dbv,
                                                const int* __restrict__ knn_idx,
                                                float* __restrict__ kvT,
                                                float* __restrict__ kvV) {
  const int b = blockIdx.x >> 6, j0 = (blockIdx.x & 63) * 16;
  const int w = threadIdx.x >> 6, l = threadIdx.x & 63;
  float* dstT = kvT + (size_t)b * D_ * 1024;
  float* dstV = kvV + (size_t)b * 1024 * D_;
  for (int jj = w; jj < 16; jj += 4) {
    const int j = j0 + jj;
    const int row = knn_idx[b * 1024 + j];
    const float4 kv = ((const float4*)(dbk + (size_t)row * D_))[l];
    dstT[(4 * l + 0) * 1024 + j] = kv.x;
    dstT[(4 * l + 1) * 1024 + j] = kv.y;
    dstT[(4 * l + 2) * 1024 + j] = kv.z;
    dstT[(4 * l + 3) * 1024 + j] = kv.w;
    const float4 vv = ((const float4*)(dbv + (size_t)row * D_))[l];
    ((float4*)(dstV + (size_t)j * D_))[l] = vv;
  }
}

// ---------------- attention: one block per (b, i) ----------------
__global__ __launch_bounds__(256) void k_attn(const float* __restrict__ qarr,
                                              const float* __restrict__ kvT,
                                              const float* __restrict__ kvV,
                                              float* __restrict__ attout) {
  __shared__ float qrow[D_];
  __shared__ float attw[1024];
  __shared__ float red1[4], red2[4];
  const int b = blockIdx.x >> 10, i = blockIdx.x & 1023;
  const int t = threadIdx.x;
  const int nk = i + 1;
  qrow[t] = qarr[((size_t)b * S_ + i) * D_ + t];
  __syncthreads();
  const int cmax = (nk + 255) >> 8;
  const float scale = 0.0625f;
  float sc[4]; float mloc = NEG_INF;
#pragma unroll
  for (int c = 0; c < 4; ++c) {
    sc[c] = NEG_INF;
    if (c < cmax) {
      const int j = c * 256 + t;
      float a = 0.f;
      const float* kp = kvT + (size_t)b * D_ * 1024 + j;
#pragma unroll 8
      for (int d = 0; d < D_; ++d) a = fmaf(qrow[d], kp[(size_t)d * 1024], a);
      if (j < nk) sc[c] = a * scale;
    }
    mloc = fmaxf(mloc, sc[c]);
  }
#pragma unroll
  for (int off = 32; off; off >>= 1) mloc = fmaxf(mloc, __shfl_down(mloc, off));
  if ((t & 63) == 0) red1[t >> 6] = mloc;
  __syncthreads();
  const float mmax = fmaxf(fmaxf(red1[0], red1[1]), fmaxf(red1[2], red1[3]));
  float sloc = 0.f; float pv[4];
#pragma unroll
  for (int c = 0; c < 4; ++c) {
    pv[c] = (sc[c] > NEG_INF * 0.5f) ? __expf(sc[c] - mmax) : 0.f;
    sloc += pv[c];
  }
#pragma unroll
  for (int off = 32; off; off >>= 1) sloc += __shfl_down(sloc, off);
  if ((t & 63) == 0) red2[t >> 6] = sloc;
  __syncthreads();
  const float inv = 1.f / (red2[0] + red2[1] + red2[2] + red2[3]);
#pragma unroll
  for (int c = 0; c < 4; ++c)
    if (c < cmax) attw[c * 256 + t] = pv[c] * inv;
  __syncthreads();
  const float* vb = kvV + (size_t)b * 1024 * D_;
  float a0 = 0.f, a1 = 0.f, a2 = 0.f, a3 = 0.f;
  int j = 0;
  for (; j + 4 <= nk; j += 4) {
    a0 = fmaf(attw[j + 0], vb[(size_t)(j + 0) * D_ + t], a0);
    a1 = fmaf(attw[j + 1], vb[(size_t)(j + 1) * D_ + t], a1);
    a2 = fmaf(attw[j + 2], vb[(size_t)(j + 2) * D_ + t], a2);
    a3 = fmaf(attw[j + 3], vb[(size_t)(j + 3) * D_ + t], a3);
  }
  for (; j < nk; ++j) a0 = fmaf(attw[j], vb[(size_t)j * D_ + t], a0);
  attout[((size_t)b * S_ + i) * D_ + t] = (a0 + a1) + (a2 + a3);
}

// ---------------- y = (attout @ wv_in) @ wv_out, one block per token ----------------
__global__ __launch_bounds__(256) void k_out(const float* __restrict__ attout,
                                             const float* __restrict__ wv_in,
                                             const float* __restrict__ wv_out,
                                             float* __restrict__ y) {
  __shared__ float row[D_];
  __shared__ float part[8][R_];
  __shared__ float t32[R_];
  const int m = blockIdx.x, t = threadIdx.x;
  row[t] = attout[(size_t)m * D_ + t];
  __syncthreads();
  const int r = t & 31, c = t >> 5;
  float p = 0.f;
#pragma unroll
  for (int d = c * 32; d < c * 32 + 32; ++d)
    p = fmaf(row[d], wv_in[d * R_ + r], p);
  part[c][r] = p;
  __syncthreads();
  if (t < R_) {
    float s = 0.f;
#pragma unroll
    for (int cc = 0; cc < 8; ++cc) s += part[cc][t];
    t32[t] = s;
  }
  __syncthreads();
  for (int hh = t; hh < H_; hh += 256) {
    float a = 0.f;
#pragma unroll
    for (int rr = 0; rr < R_; ++rr) a = fmaf(t32[rr], wv_out[rr * H_ + hh], a);
    y[(size_t)m * H_ + hh] = a;
  }
}

extern "C" void kernel_launch(void* const* d_in, const int* in_sizes, int n_in,
                              void* d_out, int out_size, void* d_ws, size_t ws_size,
                              hipStream_t stream) {
  const float* hidden  = (const float*)d_in[0];
  const float* db_keys = (const float*)d_in[1];
  const float* db_vals = (const float*)d_in[2];
  const float* wq_in   = (const float*)d_in[3];
  const float* wq_out  = (const float*)d_in[4];
  const float* wv_in   = (const float*)d_in[5];
  const float* wv_out  = (const float*)d_in[6];
  float* out = (float*)d_out;

  char* ws = (char*)d_ws;
  float*    q      = (float*)(ws + OFF_Q);
  float*    kn     = (float*)(ws + OFF_KN);
  int*      idx    = (int*)  (ws + OFF_IDX);
  int*      cand   = (int*)  (ws + OFF_CAND);
  float*    kvT    = (float*)(ws + OFF_KVT);
  float*    attout = (float*)(ws + OFF_AO);
  float*    kvV    = (float*)(ws + OFF_KVV);
  ushort_t* dbk16  = (ushort_t*)(ws + OFF_DBK16);
  // ps/pi overlay kvT/kvV (fully consumed before k_gather writes them)
  float*    ps     = (float*)(ws + OFF_KVT);
  int*      pi     = (int*)  (ws + OFF_KVV);

  const size_t need = (size_t)OFF_DBK16 + (size_t)NDB_ * D_ * 2;

  k_compute_q<<<B_ * S_, 256, 0, stream>>>(hidden, wq_in, wq_out, q);
  if (ws_size >= need) {
    // swapped-operand bf16 MFMA candidate path + exact fp32 rescore
    k_kn_cvt<<<(NDB_ + KN_PAD + 3) / 4, 256, 0, stream>>>(db_keys, kn, dbk16);
    k_knn_mfma<<<dim3(NSEL / MTQ, NCHUNK), 256, 0, stream>>>(q, dbk16, kn, ps, pi);
    k_knn_merge16<<<NSEL, 64, 0, stream>>>(ps, pi, cand, NCHUNK);
    k_rescore<<<NSEL, 256, 0, stream>>>(q, db_keys, kn, cand, idx);
  } else {
    // fp32 fallback
    k_kn<<<(NDB_ + 3) / 4, 256, 0, stream>>>(db_keys, kn);
    k_knn_partial<<<dim3(FB_NCHUNK, 8), 256, 0, stream>>>(q, db_keys, kn, ps, pi);
    k_knn_merge4<<<NSEL, 64, 0, stream>>>(ps, pi, idx, FB_NCHUNK);
  }
  k_gather<<<2 * 64, 256, 0, stream>>>(db_keys, db_vals, idx, kvT, kvV);
  k_attn<<<B_ * S_, 256, 0, stream>>>(q, kvT, kvV, attout);
  k_out<<<B_ * S_, 256, 0, stream>>>(attout, wv_in, wv_out, out);
}

// Round 6
// 575.680 us; speedup vs baseline: 1.1225x; 1.1225x over previous
//
#include <hip/hip_runtime.h>
#include <cfloat>

// Problem constants (MoMEAdaptor): B=2,S=1024,H=2048,D=256,R=32,K=4,NDB=100000
#define B_   2
#define S_   1024
#define H_   2048
#define D_   256
#define R_   32
#define K_   4
#define NDB_ 100000
#define KN_PAD 2048

// Only queries (b, t<256) feed the attention (mask j<=i => j<1024 => t<256).
#define TSEL 256
#define NSEL (B_ * TSEL)          // 512 queries that need k-NN

// fp8 MFMA knn tiling
#define NCHUNK     131            // db chunks
#define CHUNK_ROWS 768            // 6 tiles * 128
#define TILES      6
#define MTQ        128            // queries per block

// fp32 fallback tiling
#define FB_NCHUNK     61
#define FB_CHUNK_ROWS 1664
#define FB_TILES      13
#define MT         64
#define KC         64
#define LSTR       68

#define NEG_INF  (-3.0e38f)
#define IDX_MAX  0x7fffffff

// Workspace layout (bytes). need = 0x900000 + 25.6MB ~= 35 MB
// ps overlays KVT, pi overlays KVV (consumed before k_gather writes them).
#define OFF_Q     0          // 2048*256 f32            (2 MB)
#define OFF_KN    0x200000   // (100000+2048) f32
#define OFF_IDX   0x280000   // 2048 i32
#define OFF_CAND  0x290000   // 512*16 i32
#define OFF_KVT   0x300000   // keys transposed [2][256][1024] f32 (2 MB) | ps overlay
#define OFF_AO    0x500000   // attention out [2048][256] f32 (2 MB)
#define OFF_KVV   0x700000   // values dense [2][1024][256] f32 (2 MB)   | pi overlay
#define OFF_DBK8  0x900000   // fp8 db copy 100000*256 = 25.6 MB

typedef unsigned short ushort_t;
typedef unsigned int   uint_t;
typedef unsigned char  uchar_t;
typedef unsigned long long ull_t;
typedef __attribute__((ext_vector_type(16))) float f32x16;

// sorted-insert of (score,idx) into descending top-4; ties -> lower index first
__device__ __forceinline__ void ins4(float sc, int n, float s[4], int id[4]) {
  if (sc > s[3] || (sc == s[3] && n < id[3])) {
    s[3] = sc; id[3] = n;
#pragma unroll
    for (int k = 3; k > 0; --k) {
      if (s[k] > s[k - 1] || (s[k] == s[k - 1] && id[k] < id[k - 1])) {
        float ts = s[k]; s[k] = s[k - 1]; s[k - 1] = ts;
        int ti = id[k]; id[k] = id[k - 1]; id[k - 1] = ti;
      }
    }
  }
}

// ---- fp32 -> OCP e4m3fn (RNE), manual fallback ----
__device__ __forceinline__ uint_t f32_to_e4m3(float x) {
  uint_t u = __float_as_uint(x);
  uint_t sgn = (u >> 31) << 7;
  float ax = fabsf(x);
  if (!(ax < 448.f)) return sgn | 0x7e;
  if (ax < 0.015625f) {
    uint_t m = (uint_t)rintf(ax * 512.f);
    return sgn | m;
  }
  uint_t mant = u & 0x7fffffu;
  uint_t exp  = (u >> 23) & 0xffu;
  uint_t keep = mant >> 20;
  uint_t rest = mant & 0xfffffu;
  uint_t rnd  = (rest > 0x80000u) || (rest == 0x80000u && (keep & 1u));
  uint_t qq = ((exp << 3) | keep) + rnd;
  exp = qq >> 3; keep = qq & 7u;
  int e8 = (int)exp - 120;
  if (e8 >= 16) return sgn | 0x7e;
  return sgn | ((uint_t)e8 << 3) | keep;
}

#if defined(__has_builtin)
#if __has_builtin(__builtin_amdgcn_cvt_pk_fp8_f32)
#define HAVE_CVT_FP8 1
#endif
#endif

__device__ __forceinline__ uint_t pk4_fp8(float a, float b, float c, float d) {
#ifdef HAVE_CVT_FP8
  int v = 0;
  v = __builtin_amdgcn_cvt_pk_fp8_f32(a, b, v, false);
  v = __builtin_amdgcn_cvt_pk_fp8_f32(c, d, v, true);
  return (uint_t)v;
#else
  return f32_to_e4m3(a) | (f32_to_e4m3(b) << 8) |
         (f32_to_e4m3(c) << 16) | (f32_to_e4m3(d) << 24);
#endif
}

// ---------------- q = (hidden @ wq_in) @ wq_out,  one block per token ----------------
__global__ __launch_bounds__(256) void k_compute_q(
    const float* __restrict__ hidden, const float* __restrict__ wq_in,
    const float* __restrict__ wq_out, float* __restrict__ q) {
  __shared__ float hrow[H_];
  __shared__ float part[8][R_];
  __shared__ float q1[R_];
  const int m = blockIdx.x;
  const int t = threadIdx.x;
  const float* hp = hidden + (size_t)m * H_;
  ((float4*)hrow)[t]       = ((const float4*)hp)[t];
  ((float4*)hrow)[t + 256] = ((const float4*)hp)[t + 256];
  __syncthreads();
  const int r = t & 31, c = t >> 5;
  float p = 0.f;
#pragma unroll 4
  for (int e = c * 256; e < c * 256 + 256; ++e)
    p = fmaf(hrow[e], wq_in[(size_t)e * R_ + r], p);
  part[c][r] = p;
  __syncthreads();
  if (t < R_) {
    float s = 0.f;
#pragma unroll
    for (int cc = 0; cc < 8; ++cc) s += part[cc][t];
    q1[t] = s;
  }
  __syncthreads();
  float acc = 0.f;
#pragma unroll
  for (int rr = 0; rr < R_; ++rr) acc = fmaf(q1[rr], wq_out[rr * D_ + t], acc);
  q[(size_t)m * D_ + t] = acc;
}

// ------- kn[n] = |db_keys[n]|^2 (+ fused fp8 conversion, + 1e30 tail pad) -------
__global__ __launch_bounds__(256) void k_kn_cvt8(const float* __restrict__ dbk,
                                                 float* __restrict__ kn,
                                                 uchar_t* __restrict__ dbk8) {
  const int w = threadIdx.x >> 6, l = threadIdx.x & 63;
  const int n = blockIdx.x * 4 + w;
  if (n >= NDB_ + KN_PAD) return;
  if (n >= NDB_) { if (l == 0) kn[n] = 1.0e30f; return; }
  const float4 v = ((const float4*)(dbk + (size_t)n * D_))[l];
  ((uint_t*)(dbk8 + (size_t)n * D_))[l] = pk4_fp8(v.x, v.y, v.z, v.w);
  float s = v.x * v.x + v.y * v.y + v.z * v.z + v.w * v.w;
#pragma unroll
  for (int off = 32; off; off >>= 1) s += __shfl_down(s, off);
  if (l == 0) kn[n] = s;
}

// plain kn (fallback path)
__global__ __launch_bounds__(256) void k_kn(const float* __restrict__ dbk,
                                            float* __restrict__ kn) {
  const int w = threadIdx.x >> 6, l = threadIdx.x & 63;
  const int n = blockIdx.x * 4 + w;
  if (n >= NDB_) return;
  const float4 v = ((const float4*)(dbk + (size_t)n * D_))[l];
  float s = v.x * v.x + v.y * v.y + v.z * v.z + v.w * v.w;
#pragma unroll
  for (int off = 32; off; off >>= 1) s += __shfl_down(s, off);
  if (l == 0) kn[n] = s;
}

// ---------------- fp8 MFMA knn: per-(qb, chunk) partial top-4 ----------------
// Round-4 structure (coalesced global_load_lds staging) + fp8 (half bytes) +
// MTQ=128 (half passes): demand = 4 x 25.6 MB. approx score = 2*(q.k)_fp8 - kn_fp32;
// exact fp32 rescore of global top-16 restores exact indices (score noise 0.14
// vs ~15-pt rank-4->16 margin = ~100 sigma).
// A (q fp8, 128x256B = 32KB) resident with 16B-chunk XOR swizzle + 8B-half swap
// keyed on (row>>3)&1 (kills the 4-way LDS conflict on A-frag reads).
// B (db fp8, 128x256B = 32KB) staged whole-K via global_load_lds w=16; swizzle
// folded into GLOBAL address (LDS side lane-contiguous, m104 rule).
// Scores overlay B in two 64-row halves. LDS 64KB -> 2 blocks/CU.
__global__ __launch_bounds__(256, 2) void k_knn_mfma8(
    const float* __restrict__ q, const uchar_t* __restrict__ dbk8,
    const float* __restrict__ kn, float* __restrict__ pscore,
    int* __restrict__ pidx) {
  __shared__ __align__(16) char smem[65536];
  uchar_t* sA8 = (uchar_t*)smem;             // 128 rows x 256B
  uchar_t* sB8 = (uchar_t*)(smem + 32768);   // 128 rows x 256B
  float*   sS  = (float*)(smem + 32768);     // scores [64 m][128 n] overlay on B

  const int tid = threadIdx.x;
  const int wv = tid >> 6, ln = tid & 63;
  const int lm = ln & 31, lh = ln >> 5;
  const int tx = tid & 15, ty = tid >> 4;
  const int qb = blockIdx.x, chunk = blockIdx.y;
  const int row_base = chunk * CHUNK_ROWS;

  // ---- stage A once: 128 selected q rows -> fp8, chunk-XOR swizzle + half swap ----
  {
    const int m = tid >> 1, h = tid & 1;
    const int sq = qb * MTQ + m;
    const float* qp = q + ((size_t)((sq >> 8) * S_ + (sq & 255))) * D_;
    const int sw = (m >> 3) & 1;
#pragma unroll
    for (int pi = 0; pi < 8; ++pi) {
      const int p = h * 8 + pi;
      const int c = p ^ (m & 15);
      const float4 v0 = *(const float4*)(qp + c * 16);
      const float4 v1 = *(const float4*)(qp + c * 16 + 4);
      const float4 v2 = *(const float4*)(qp + c * 16 + 8);
      const float4 v3 = *(const float4*)(qp + c * 16 + 12);
      const ull_t lo = (ull_t)pk4_fp8(v0.x, v0.y, v0.z, v0.w) |
                       ((ull_t)pk4_fp8(v1.x, v1.y, v1.z, v1.w) << 32);
      const ull_t hi = (ull_t)pk4_fp8(v2.x, v2.y, v2.z, v2.w) |
                       ((ull_t)pk4_fp8(v3.x, v3.y, v3.z, v3.w) << 32);
      *(ull_t*)&sA8[m * 256 + p * 16 + sw * 8]       = lo;
      *(ull_t*)&sA8[m * 256 + p * 16 + (sw ^ 1) * 8] = hi;
    }
  }

  float s4[8][4]; int i4[8][4];
#pragma unroll
  for (int g = 0; g < 8; ++g)
#pragma unroll
    for (int k = 0; k < 4; ++k) { s4[g][k] = NEG_INF; i4[g][k] = IDX_MAX; }

  const int nB = wv * 32 + lm;
  const int aswz = lm & 15;
  const int ahalf = (lm >> 3) & 1;

  for (int tile = 0; tile < TILES; ++tile) {
    const int row0 = row_base + tile * 128;

    __syncthreads();   // prior sS readers done (tile0: A staged)
    // ---- stage B whole-K: wave wv stages rows [wv*32, wv*32+32) ----
    {
      const int n_in = ln >> 4;
      const int p    = ln & 15;
#pragma unroll
      for (int i = 0; i < 8; ++i) {
        const int r0l = wv * 32 + i * 4;
        const int nloc = r0l + n_in;
        int krow = row0 + nloc; if (krow >= NDB_) krow = NDB_ - 1;
        const int c = p ^ (nloc & 15);
        const uchar_t* gp = dbk8 + (size_t)krow * D_ + c * 16;
        uchar_t* lp = sB8 + (size_t)r0l * 256;   // wave-uniform base
        __builtin_amdgcn_global_load_lds(
            (const __attribute__((address_space(1))) void*)gp,
            (__attribute__((address_space(3))) void*)lp, 16, 0, 0);
      }
    }
    __syncthreads();

    // ---- MFMA: 16 ksteps of K=16, 4 m-groups (128 q) x 32 n per wave ----
    f32x16 acc[4];
#pragma unroll
    for (int g = 0; g < 4; ++g)
#pragma unroll
      for (int r = 0; r < 16; ++r) acc[g][r] = 0.f;
#pragma unroll
    for (int s = 0; s < 16; ++s) {
      const int off  = (s ^ aswz) * 16;
      const int aoff = off + ((lh ^ ahalf) * 8);
      const int boff = off + lh * 8;
      const long bb = *(const long*)&sB8[nB * 256 + boff];
#pragma unroll
      for (int g = 0; g < 4; ++g) {
        const long aa = *(const long*)&sA8[(g * 32 + lm) * 256 + aoff];
        acc[g] = __builtin_amdgcn_mfma_f32_32x32x16_fp8_fp8(aa, bb, acc[g], 0, 0, 0);
      }
    }

    // kn for this tile's 8 columns owned at select
    const int nbase = row0 + tx * 8;
    float knv[8];
#pragma unroll
    for (int j = 0; j < 8; ++j)
      knv[j] = kn[nbase + j];          // padded tail = 1e30 self-excludes

    // ---- two select halves through the 32KB sS overlay ----
#pragma unroll
    for (int h = 0; h < 2; ++h) {
      __syncthreads();   // B reads (h=0) / prior select (h=1) done
#pragma unroll
      for (int gg = 0; gg < 2; ++gg) {
        const int g = 2 * h + gg;
#pragma unroll
        for (int r = 0; r < 16; ++r) {
          const int mrow = (r & 3) + 8 * (r >> 2) + 4 * lh;
          sS[(gg * 32 + mrow) * 128 + nB] = acc[g][r];
        }
      }
      __syncthreads();
      // select: thread = 8 n cols x 4 m rows (of this 64-row half)
#pragma unroll
      for (int qi = 0; qi < 4; ++qi) {
        const int ml = ty * 4 + qi;
        const float4 v0 = *(const float4*)&sS[ml * 128 + tx * 8];
        const float4 v1 = *(const float4*)&sS[ml * 128 + tx * 8 + 4];
        const float sv[8] = {v0.x, v0.y, v0.z, v0.w, v1.x, v1.y, v1.z, v1.w};
        float v[8];
#pragma unroll
        for (int j = 0; j < 8; ++j) v[j] = fmaf(2.f, sv[j], -knv[j]);
        const float mx = fmaxf(fmaxf(fmaxf(v[0], v[1]), fmaxf(v[2], v[3])),
                               fmaxf(fmaxf(v[4], v[5]), fmaxf(v[6], v[7])));
        const int sidx = h * 4 + qi;
        if (mx >= s4[sidx][3]) {
#pragma unroll
          for (int j = 0; j < 8; ++j) ins4(v[j], nbase + j, s4[sidx], i4[sidx]);
        }
      }
    }
  }

  // ---- block merge per 64-row half: 64 cand-sets of 4 -> top-4 per (query,chunk) ----
  // Both overlays stride 65 (the round-3 bug was ci stride 63 < 64 slots -> collision).
  float* cs = (float*)smem;                   // 64*65*4 = 16640 B
  int*   ci = (int*)(smem + 16640);           // 64*65*4 = 16640 B  (total 33280 <= 64K)
#pragma unroll
  for (int h = 0; h < 2; ++h) {
    __syncthreads();
#pragma unroll
    for (int qi = 0; qi < 4; ++qi) {
      const int qrow = ty * 4 + qi;
#pragma unroll
      for (int k = 0; k < 4; ++k) {
        cs[qrow * 65 + tx * 4 + k] = s4[h * 4 + qi][k];
        ci[qrow * 65 + tx * 4 + k] = i4[h * 4 + qi][k];
      }
    }
    __syncthreads();
    if (tid < 64) {
      float fs[4]; int fi[4];
#pragma unroll
      for (int k = 0; k < 4; ++k) { fs[k] = NEG_INF; fi[k] = IDX_MAX; }
      for (int c = 0; c < 64; ++c)
        ins4(cs[tid * 65 + c], ci[tid * 65 + c], fs, fi);
      const int sq = qb * MTQ + h * 64 + tid;
      float* po = pscore + ((size_t)sq * NCHUNK + chunk) * 4;
      int*   io = pidx   + ((size_t)sq * NCHUNK + chunk) * 4;
#pragma unroll
      for (int k = 0; k < 4; ++k) { po[k] = fs[k]; io[k] = fi[k]; }
    }
  }
}

// ---------------- fp32 fallback knn (round-1 kernel, used if ws too small) ----------------
__global__ __launch_bounds__(256) void k_knn_partial(
    const float* __restrict__ q, const float* __restrict__ dbk,
    const float* __restrict__ kn, float* __restrict__ pscore,
    int* __restrict__ pidx) {
  __shared__ float smem[3 * KC * LSTR];
  float* sA  = smem;
  float* sB0 = smem + KC * LSTR;
  float* sB1 = smem + 2 * KC * LSTR;
  const int tid = threadIdx.x;
  const int tx = tid & 15, ty = tid >> 4;
  const int chunk = blockIdx.x, qb = blockIdx.y;
  const int arq = tid >> 2;
  const int aqd = (tid & 3) * 4;
  const int brk = tid >> 1;
  const int bh  = tid & 1;
  const int bcol = ((brk >> 3) << 2) | (brk & 3);
  float* sBw = (brk & 4) ? sB1 : sB0;
  const int sq_a = qb * MT + arq;
  const float* qsrc = q + ((size_t)((sq_a >> 8) * S_ + (sq_a & 255))) * D_;
  float s4[4][4]; int i4[4][4];
#pragma unroll
  for (int a = 0; a < 4; ++a)
#pragma unroll
    for (int b = 0; b < 4; ++b) { s4[a][b] = NEG_INF; i4[a][b] = IDX_MAX; }
  const int row_base = chunk * FB_CHUNK_ROWS;
  for (int tile = 0; tile < FB_TILES; ++tile) {
    const int row0 = row_base + tile * 128;
    if (row0 >= NDB_) break;
    int krow = row0 + brk; if (krow >= NDB_) krow = NDB_ - 1;
    const float* ksrc = dbk + (size_t)krow * D_;
    float acc[4][8];
#pragma unroll
    for (int a = 0; a < 4; ++a)
#pragma unroll
      for (int b = 0; b < 8; ++b) acc[a][b] = 0.f;
    for (int kc = 0; kc < 4; ++kc) {
      __syncthreads();
#pragma unroll
      for (int p = 0; p < 4; ++p) {
        const int kkl = p * 16 + aqd;
        const float4 v = *(const float4*)(qsrc + kc * KC + kkl);
        sA[(kkl + 0) * LSTR + arq] = v.x;
        sA[(kkl + 1) * LSTR + arq] = v.y;
        sA[(kkl + 2) * LSTR + arq] = v.z;
        sA[(kkl + 3) * LSTR + arq] = v.w;
      }
#pragma unroll
      for (int p = 0; p < 8; ++p) {
        const int kkl = bh * 32 + p * 4;
        const float4 v = *(const float4*)(ksrc + kc * KC + kkl);
        sBw[(kkl + 0) * LSTR + bcol] = v.x;
        sBw[(kkl + 1) * LSTR + bcol] = v.y;
        sBw[(kkl + 2) * LSTR + bcol] = v.z;
        sBw[(kkl + 3) * LSTR + bcol] = v.w;
      }
      __syncthreads();
#pragma unroll 4
      for (int kk = 0; kk < KC; ++kk) {
        const float4 a  = *(const float4*)&sA [kk * LSTR + ty * 4];
        const float4 b0 = *(const float4*)&sB0[kk * LSTR + tx * 4];
        const float4 b1 = *(const float4*)&sB1[kk * LSTR + tx * 4];
        const float av[4] = {a.x, a.y, a.z, a.w};
        const float bv[8] = {b0.x, b0.y, b0.z, b0.w, b1.x, b1.y, b1.z, b1.w};
#pragma unroll
        for (int qi = 0; qi < 4; ++qi)
#pragma unroll
          for (int nj = 0; nj < 8; ++nj)
            acc[qi][nj] = fmaf(av[qi], bv[nj], acc[qi][nj]);
      }
    }
#pragma unroll
    for (int nj = 0; nj < 8; ++nj) {
      const int n = row0 + tx * 8 + nj;
      if (n < NDB_) {
        const float knj = kn[n];
        ins4(2.f * acc[0][nj] - knj, n, s4[0], i4[0]);
        ins4(2.f * acc[1][nj] - knj, n, s4[1], i4[1]);
        ins4(2.f * acc[2][nj] - knj, n, s4[2], i4[2]);
        ins4(2.f * acc[3][nj] - knj, n, s4[3], i4[3]);
      }
    }
  }
  __syncthreads();
  float* cs = smem;
  int*   ci = (int*)(smem + 64 * 65);
#pragma unroll
  for (int qi = 0; qi < 4; ++qi)
#pragma unroll
    for (int k = 0; k < 4; ++k) {
      cs[(ty * 4 + qi) * 65 + tx * 4 + k] = s4[qi][k];
      ci[(ty * 4 + qi) * 65 + tx * 4 + k] = i4[qi][k];
    }
  __syncthreads();
  if (tid < 64) {
    float fs[4]; int fi[4];
#pragma unroll
    for (int k = 0; k < 4; ++k) { fs[k] = NEG_INF; fi[k] = IDX_MAX; }
    for (int c = 0; c < 64; ++c)
      ins4(cs[tid * 65 + c], ci[tid * 65 + c], fs, fi);
    const int sq = qb * MT + tid;
    float* po = pscore + ((size_t)sq * FB_NCHUNK + chunk) * 4;
    int*   io = pidx   + ((size_t)sq * FB_NCHUNK + chunk) * 4;
#pragma unroll
    for (int k = 0; k < 4; ++k) { po[k] = fs[k]; io[k] = fi[k]; }
  }
}

// ---------------- merge chunk candidates -> sorted global top-R ----------------
template <int RANKS>
__device__ __forceinline__ void merge_top(const float* __restrict__ pscore,
                                          const int* __restrict__ pidx,
                                          int* __restrict__ outp, int nch) {
  const int sq = blockIdx.x, l = threadIdx.x;
  float s4[4]; int i4[4];
#pragma unroll
  for (int k = 0; k < 4; ++k) { s4[k] = NEG_INF; i4[k] = IDX_MAX; }
  for (int c = l; c < nch * 4; c += 64)
    ins4(pscore[(size_t)sq * nch * 4 + c], pidx[(size_t)sq * nch * 4 + c], s4, i4);
#pragma unroll
  for (int r = 0; r < RANKS; ++r) {
    float s = s4[0]; int i = i4[0];
#pragma unroll
    for (int off = 32; off; off >>= 1) {
      float so = __shfl_down(s, off); int io = __shfl_down(i, off);
      if (so > s || (so == s && io < i)) { s = so; i = io; }
    }
    const float sw = __shfl(s, 0); const int iw = __shfl(i, 0);
    if (l == 0) outp[sq * RANKS + r] = iw;
    if (s4[0] == sw && i4[0] == iw) {
      s4[0] = s4[1]; i4[0] = i4[1];
      s4[1] = s4[2]; i4[1] = i4[2];
      s4[2] = s4[3]; i4[2] = i4[3];
      s4[3] = NEG_INF; i4[3] = IDX_MAX;
    }
  }
}

__global__ __launch_bounds__(64) void k_knn_merge4(const float* __restrict__ ps,
                                                   const int* __restrict__ pi,
                                                   int* __restrict__ knn_idx, int nch) {
  merge_top<4>(ps, pi, knn_idx, nch);
}
__global__ __launch_bounds__(64) void k_knn_merge16(const float* __restrict__ ps,
                                                    const int* __restrict__ pi,
                                                    int* __restrict__ cand, int nch) {
  merge_top<16>(ps, pi, cand, nch);
}

// ---------------- exact fp32 rescore of 16 candidates -> final sorted top-4 ----------------
__global__ __launch_bounds__(256) void k_rescore(const float* __restrict__ q,
                                                 const float* __restrict__ dbk,
                                                 const float* __restrict__ kn,
                                                 const int* __restrict__ cand,
                                                 int* __restrict__ knn_idx) {
  __shared__ float scs[16];
  __shared__ int   sci[16];
  const int sq = blockIdx.x, wv = threadIdx.x >> 6, l = threadIdx.x & 63;
  const float* qp = q + ((size_t)((sq >> 8) * S_ + (sq & 255))) * D_;
  const float4 qv = ((const float4*)qp)[l];
  for (int cc = wv; cc < 16; cc += 4) {
    const int n = cand[sq * 16 + cc];
    const float4 kv = ((const float4*)(dbk + (size_t)n * D_))[l];
    float s = qv.x * kv.x + qv.y * kv.y + qv.z * kv.z + qv.w * kv.w;
#pragma unroll
    for (int off = 32; off; off >>= 1) s += __shfl_down(s, off);
    if (l == 0) { scs[cc] = 2.f * s - kn[n]; sci[cc] = n; }
  }
  __syncthreads();
  if (threadIdx.x == 0) {
    float s4[4]; int i4[4];
#pragma unroll
    for (int k = 0; k < 4; ++k) { s4[k] = NEG_INF; i4[k] = IDX_MAX; }
#pragma unroll
    for (int c = 0; c < 16; ++c) ins4(scs[c], sci[c], s4, i4);
#pragma unroll
    for (int k = 0; k < 4; ++k) knn_idx[sq * 4 + k] = i4[k];
  }
}

// -------- gather: keys transposed kvT[b][d][j] + values dense kvV[b][j][d] --------
__global__ __launch_bounds__(256) void k_gather(const float* __restrict__ dbk,
                                                const float* __restrict__ dbv,
                                                const int* __restrict__ knn_idx,
                                                float* __restrict__ kvT,
                                                float* __restrict__ kvV) {
  const int b = blockIdx.x >> 6, j0 = (blockIdx.x & 63) * 16;
  const int w = threadIdx.x >> 6, l = threadIdx.x & 63;
  float* dstT = kvT + (size_t)b * D_ * 1024;
  float* dstV = kvV + (size_t)b * 1024 * D_;
  for (int jj = w; jj < 16; jj += 4) {
    const int j = j0 + jj;
    const int row = knn_idx[b * 1024 + j];
    const float4 kv = ((const float4*)(dbk + (size_t)row * D_))[l];
    dstT[(4 * l + 0) * 1024 + j] = kv.x;
    dstT[(4 * l + 1) * 1024 + j] = kv.y;
    dstT[(4 * l + 2) * 1024 + j] = kv.z;
    dstT[(4 * l + 3) * 1024 + j] = kv.w;
    const float4 vv = ((const float4*)(dbv + (size_t)row * D_))[l];
    ((float4*)(dstV + (size_t)j * D_))[l] = vv;
  }
}

// ---------------- attention: one block per (b, i) ----------------
__global__ __launch_bounds__(256) void k_attn(const float* __restrict__ qarr,
                                              const float* __restrict__ kvT,
                                              const float* __restrict__ kvV,
                                              float* __restrict__ attout) {
  __shared__ float qrow[D_];
  __shared__ float attw[1024];
  __shared__ float red1[4], red2[4];
  const int b = blockIdx.x >> 10, i = blockIdx.x & 1023;
  const int t = threadIdx.x;
  const int nk = i + 1;
  qrow[t] = qarr[((size_t)b * S_ + i) * D_ + t];
  __syncthreads();
  const int cmax = (nk + 255) >> 8;
  const float scale = 0.0625f;
  float sc[4]; float mloc = NEG_INF;
#pragma unroll
  for (int c = 0; c < 4; ++c) {
    sc[c] = NEG_INF;
    if (c < cmax) {
      const int j = c * 256 + t;
      float a = 0.f;
      const float* kp = kvT + (size_t)b * D_ * 1024 + j;
#pragma unroll 8
      for (int d = 0; d < D_; ++d) a = fmaf(qrow[d], kp[(size_t)d * 1024], a);
      if (j < nk) sc[c] = a * scale;
    }
    mloc = fmaxf(mloc, sc[c]);
  }
#pragma unroll
  for (int off = 32; off; off >>= 1) mloc = fmaxf(mloc, __shfl_down(mloc, off));
  if ((t & 63) == 0) red1[t >> 6] = mloc;
  __syncthreads();
  const float mmax = fmaxf(fmaxf(red1[0], red1[1]), fmaxf(red1[2], red1[3]));
  float sloc = 0.f; float pv[4];
#pragma unroll
  for (int c = 0; c < 4; ++c) {
    pv[c] = (sc[c] > NEG_INF * 0.5f) ? __expf(sc[c] - mmax) : 0.f;
    sloc += pv[c];
  }
#pragma unroll
  for (int off = 32; off; off >>= 1) sloc += __shfl_down(sloc, off);
  if ((t & 63) == 0) red2[t >> 6] = sloc;
  __syncthreads();
  const float inv = 1.f / (red2[0] + red2[1] + red2[2] + red2[3]);
#pragma unroll
  for (int c = 0; c < 4; ++c)
    if (c < cmax) attw[c * 256 + t] = pv[c] * inv;
  __syncthreads();
  const float* vb = kvV + (size_t)b * 1024 * D_;
  float a0 = 0.f, a1 = 0.f, a2 = 0.f, a3 = 0.f;
  int j = 0;
  for (; j + 4 <= nk; j += 4) {
    a0 = fmaf(attw[j + 0], vb[(size_t)(j + 0) * D_ + t], a0);
    a1 = fmaf(attw[j + 1], vb[(size_t)(j + 1) * D_ + t], a1);
    a2 = fmaf(attw[j + 2], vb[(size_t)(j + 2) * D_ + t], a2);
    a3 = fmaf(attw[j + 3], vb[(size_t)(j + 3) * D_ + t], a3);
  }
  for (; j < nk; ++j) a0 = fmaf(attw[j], vb[(size_t)j * D_ + t], a0);
  attout[((size_t)b * S_ + i) * D_ + t] = (a0 + a1) + (a2 + a3);
}

// ---------------- y = (attout @ wv_in) @ wv_out, one block per token ----------------
__global__ __launch_bounds__(256) void k_out(const float* __restrict__ attout,
                                             const float* __restrict__ wv_in,
                                             const float* __restrict__ wv_out,
                                             float* __restrict__ y) {
  __shared__ float row[D_];
  __shared__ float part[8][R_];
  __shared__ float t32[R_];
  const int m = blockIdx.x, t = threadIdx.x;
  row[t] = attout[(size_t)m * D_ + t];
  __syncthreads();
  const int r = t & 31, c = t >> 5;
  float p = 0.f;
#pragma unroll
  for (int d = c * 32; d < c * 32 + 32; ++d)
    p = fmaf(row[d], wv_in[d * R_ + r], p);
  part[c][r] = p;
  __syncthreads();
  if (t < R_) {
    float s = 0.f;
#pragma unroll
    for (int cc = 0; cc < 8; ++cc) s += part[cc][t];
    t32[t] = s;
  }
  __syncthreads();
  for (int hh = t; hh < H_; hh += 256) {
    float a = 0.f;
#pragma unroll
    for (int rr = 0; rr < R_; ++rr) a = fmaf(t32[rr], wv_out[rr * H_ + hh], a);
    y[(size_t)m * H_ + hh] = a;
  }
}

extern "C" void kernel_launch(void* const* d_in, const int* in_sizes, int n_in,
                              void* d_out, int out_size, void* d_ws, size_t ws_size,
                              hipStream_t stream) {
  const float* hidden  = (const float*)d_in[0];
  const float* db_keys = (const float*)d_in[1];
  const float* db_vals = (const float*)d_in[2];
  const float* wq_in   = (const float*)d_in[3];
  const float* wq_out  = (const float*)d_in[4];
  const float* wv_in   = (const float*)d_in[5];
  const float* wv_out  = (const float*)d_in[6];
  float* out = (float*)d_out;

  char* ws = (char*)d_ws;
  float*   q      = (float*)(ws + OFF_Q);
  float*   kn     = (float*)(ws + OFF_KN);
  int*     idx    = (int*)  (ws + OFF_IDX);
  int*     cand   = (int*)  (ws + OFF_CAND);
  float*   kvT    = (float*)(ws + OFF_KVT);
  float*   attout = (float*)(ws + OFF_AO);
  float*   kvV    = (float*)(ws + OFF_KVV);
  uchar_t* dbk8   = (uchar_t*)(ws + OFF_DBK8);
  // ps/pi overlay kvT/kvV (fully consumed before k_gather writes them)
  float*   ps     = (float*)(ws + OFF_KVT);
  int*     pi     = (int*)  (ws + OFF_KVV);

  const size_t need = (size_t)OFF_DBK8 + (size_t)NDB_ * D_;

  k_compute_q<<<B_ * S_, 256, 0, stream>>>(hidden, wq_in, wq_out, q);
  if (ws_size >= need) {
    // fp8 MFMA candidate path (MTQ=128, demand 4x25.6MB) + exact fp32 rescore
    k_kn_cvt8<<<(NDB_ + KN_PAD + 3) / 4, 256, 0, stream>>>(db_keys, kn, dbk8);
    k_knn_mfma8<<<dim3(NSEL / MTQ, NCHUNK), 256, 0, stream>>>(q, dbk8, kn, ps, pi);
    k_knn_merge16<<<NSEL, 64, 0, stream>>>(ps, pi, cand, NCHUNK);
    k_rescore<<<NSEL, 256, 0, stream>>>(q, db_keys, kn, cand, idx);
  } else {
    // fp32 fallback
    k_kn<<<(NDB_ + 3) / 4, 256, 0, stream>>>(db_keys, kn);
    k_knn_partial<<<dim3(FB_NCHUNK, 8), 256, 0, stream>>>(q, db_keys, kn, ps, pi);
    k_knn_merge4<<<NSEL, 64, 0, stream>>>(ps, pi, idx, FB_NCHUNK);
  }
  k_gather<<<2 * 64, 256, 0, stream>>>(db_keys, db_vals, idx, kvT, kvV);
  k_attn<<<B_ * S_, 256, 0, stream>>>(q, kvT, kvV, attout);
  k_out<<<B_ * S_, 256, 0, stream>>>(attout, wv_in, wv_out, out);
}